// Round 1
// baseline (332.474 us; speedup 1.0000x reference)
//
#include <hip/hip_runtime.h>
#include <hip/hip_bf16.h>
#include <math.h>

namespace {
constexpr int kH = 384, kW = 384, kBn = 2;
constexpr int kHW = kH * kW;       // 147456
constexpr int kOMD = 112;
constexpr int kNB = kBn * (kHW / 64);   // 4608 blocks
constexpr int kNB8 = kNB / 8;           // 576 per XCD
}

__device__ __forceinline__ int swz(int bid) {
    // XCD-aware: round-robin dispatch -> each XCD gets a contiguous range
    return (bid & 7) * kNB8 + (bid >> 3);
}

__device__ __forceinline__ void fma4(float* acc, float a, float4 w) {
    acc[0] = fmaf(a, w.x, acc[0]);
    acc[1] = fmaf(a, w.y, acc[1]);
    acc[2] = fmaf(a, w.z, acc[2]);
    acc[3] = fmaf(a, w.w, acc[3]);
}

// bf16 pair unpack (packed in a uint32: low ushort = even channel, high = odd)
__device__ __forceinline__ float bl(unsigned u) {
    return __uint_as_float(u << 16);
}
__device__ __forceinline__ float bh(unsigned u) {
    return __uint_as_float(u & 0xffff0000u);
}
__device__ __forceinline__ unsigned short f2bf(float f) {
    union { __hip_bfloat16 b; unsigned short s; } u;
    u.b = __float2bfloat16(f);   // RNE
    return u.s;
}

// K1: value[b][g][yx][c16] (bf16) = inp(b,:,yx) @ Wv + bv
// Stage-D pattern: wave g owns out-channels g*16..g*16+15 (= group g),
// weights via wave-uniform scalar loads (SGPR broadcast, off the LDS pipe);
// activations staged transposed in LDS, ONE ds_read_b32 per ci per thread.
__global__ __launch_bounds__(256) void k_value(
        const float* __restrict__ inp, const float* __restrict__ Wv,
        const float* __restrict__ bv, unsigned short* __restrict__ value) {
    __shared__ float xin[64][64];   // [ci][p]; row reads lane=p consecutive -> conflict-free
    const int tid = threadIdx.x;
    const int bid = swz(blockIdx.x);
    const int b = bid / (kHW / 64);
    const int pix0 = (bid % (kHW / 64)) * 64;
    const float* ib = inp + (size_t)b * 64 * kHW + pix0;
    // stage inp transposed: xin[c][p], float4 loads (64B rows contiguous)
    for (int i = tid; i < 1024; i += 256) {
        const int c = i >> 4, p4 = (i & 15) << 2;
        const float4 v = *(const float4*)(ib + (size_t)c * kHW + p4);
        *(float4*)&xin[c][p4] = v;
    }
    __syncthreads();

    const int p = tid & 63;
    const int g = __builtin_amdgcn_readfirstlane(tid >> 6);  // wave-uniform

    float acc[16];
    {
        const float* bg = bv + g * 16;          // wave-uniform -> s_load
        #pragma unroll
        for (int j = 0; j < 16; ++j) acc[j] = bg[j];
    }
    #pragma unroll 4
    for (int ci = 0; ci < 64; ++ci) {
        const float a = xin[ci][p];             // 1 ds_read_b32 / thread / ci
        const float* wr = Wv + ci * 64 + g * 16;  // wave-uniform -> s_load_dwordx16
        #pragma unroll
        for (int j = 0; j < 16; ++j) acc[j] = fmaf(a, wr[j], acc[j]);
    }

    // pack 16 channels to bf16 and store 32B coalesced (this wave's group = g)
    unsigned u[8];
    #pragma unroll
    for (int j = 0; j < 8; ++j)
        u[j] = (unsigned)f2bf(acc[2 * j]) | ((unsigned)f2bf(acc[2 * j + 1]) << 16);
    uint4* vo = (uint4*)(value + ((size_t)(b * 4 + g) * kHW + pix0 + p) * 16);
    vo[0] = make_uint4(u[0], u[1], u[2], u[3]);
    vo[1] = make_uint4(u[4], u[5], u[6], u[7]);
}

// K2: fused depthwise conv -> om matvec -> deformable sampling -> @Wo -> out
// One block = 64 consecutive pixels of one row. 256 threads.
__global__ __launch_bounds__(256) void k_main(
        const float* __restrict__ inp, const float* __restrict__ Wdw,
        const float* __restrict__ bdw, const float* __restrict__ Wom,
        const float* __restrict__ bom, const float* __restrict__ Wo,
        const unsigned short* __restrict__ value, float* __restrict__ out) {
    __shared__ float lds1[64][68];   // dw^T [c][p]; later reused as sampled^T [c][p]

    const int tid = threadIdx.x;
    const int bid = swz(blockIdx.x);
    const int b = bid / (kH * (kW / 64));
    const int rem = bid % (kH * (kW / 64));
    const int h = rem / (kW / 64);
    const int w0 = (rem % (kW / 64)) * 64;

    const int p = tid & 63;
    const int g = tid >> 6;
    const int gs = __builtin_amdgcn_readfirstlane(g);   // wave-uniform -> SGPR

    // ---- stage A: depthwise 3x3 conv (zero pad) -> lds1[c][p] ----
    {
        const int w = w0 + p;
        #pragma unroll 4
        for (int cc = 0; cc < 16; ++cc) {
            const int c = gs * 16 + cc;                 // wave-uniform
            const float* ib = inp + (size_t)(b * 64 + c) * kHW;
            float s = bdw[c];
            #pragma unroll
            for (int r = 0; r < 3; ++r) {
                const int y = h - 1 + r;
                if (y >= 0 && y < kH) {
                    const float* rowp = ib + (size_t)y * kW;
                    #pragma unroll
                    for (int kx = 0; kx < 3; ++kx) {
                        const int x = w - 1 + kx;
                        const float v = (x >= 0 && x < kW) ? rowp[x] : 0.f;
                        s = fmaf(v, Wdw[c * 9 + r * 3 + kx], s);
                    }
                }
            }
            lds1[c][p] = s;
        }
    }
    __syncthreads();

    // ---- stage B: om[27] for this (pixel p, group g), in registers ----
    float om[27];
    {
        const float* bg = bom + gs * 27;                // scalar loads
        #pragma unroll
        for (int j = 0; j < 27; ++j) om[j] = bg[j];
        #pragma unroll 4
        for (int ci = 0; ci < 64; ++ci) {
            const float a = lds1[ci][p];
            const float* wr = Wom + ci * kOMD + gs * 27;  // wave-uniform -> s_load
            #pragma unroll
            for (int j = 0; j < 27; ++j) om[j] = fmaf(a, wr[j], om[j]);
        }
    }
    __syncthreads();   // lds1 reads done; stage C will overwrite it

    // ---- stage C: deformable bilinear sampling (bf16 value, 32B/corner) ----
    {
        float acc[16];
        #pragma unroll
        for (int j = 0; j < 16; ++j) acc[j] = 0.f;
        const float fw = (float)(w0 + p);
        const float fh = (float)h;
        const unsigned short* vbase = value + (size_t)(b * 4 + gs) * kHW * 16;
        #pragma unroll
        for (int k = 0; k < 9; ++k) {
            const int ky = k / 3, kx = k % 3;
            const float dx = om[2 * k];
            const float dy = om[2 * k + 1];
            const float m = om[18 + k];
            const float px = fw + (float)(kx - 1) + dx;
            const float py = fh + (float)(ky - 1) + dy;
            const float x0f = floorf(px), y0f = floorf(py);
            const int x0 = (int)x0f, y0 = (int)y0f;
            const float wx1 = px - x0f, wy1 = py - y0f;
            const float wx0 = 1.f - wx1, wy0 = 1.f - wy1;
            #pragma unroll
            for (int cor = 0; cor < 4; ++cor) {
                const int dy2 = cor >> 1, dx2 = cor & 1;
                const int xi = x0 + dx2, yi = y0 + dy2;
                float wgt = (dy2 ? wy1 : wy0) * (dx2 ? wx1 : wx0) * m;
                if (xi < 0 || xi >= kW || yi < 0 || yi >= kH) wgt = 0.f;
                const int xc = min(max(xi, 0), kW - 1);
                const int yc = min(max(yi, 0), kH - 1);
                const uint4* vp = (const uint4*)(vbase +
                        ((size_t)yc * kW + xc) * 16);
                const uint4 u0 = vp[0];
                const uint4 u1 = vp[1];
                acc[0]  = fmaf(wgt, bl(u0.x), acc[0]);
                acc[1]  = fmaf(wgt, bh(u0.x), acc[1]);
                acc[2]  = fmaf(wgt, bl(u0.y), acc[2]);
                acc[3]  = fmaf(wgt, bh(u0.y), acc[3]);
                acc[4]  = fmaf(wgt, bl(u0.z), acc[4]);
                acc[5]  = fmaf(wgt, bh(u0.z), acc[5]);
                acc[6]  = fmaf(wgt, bl(u0.w), acc[6]);
                acc[7]  = fmaf(wgt, bh(u0.w), acc[7]);
                acc[8]  = fmaf(wgt, bl(u1.x), acc[8]);
                acc[9]  = fmaf(wgt, bh(u1.x), acc[9]);
                acc[10] = fmaf(wgt, bl(u1.y), acc[10]);
                acc[11] = fmaf(wgt, bh(u1.y), acc[11]);
                acc[12] = fmaf(wgt, bl(u1.z), acc[12]);
                acc[13] = fmaf(wgt, bh(u1.z), acc[13]);
                acc[14] = fmaf(wgt, bl(u1.w), acc[14]);
                acc[15] = fmaf(wgt, bh(u1.w), acc[15]);
            }
        }
        // write sampled result transposed into lds1 (dw is dead now)
        #pragma unroll
        for (int j = 0; j < 16; ++j) lds1[gs * 16 + j][p] = acc[j];
    }
    __syncthreads();

    // ---- stage D: final @Wo, coalesced (B,C,H,W) writeout ----
    {
        const int cg = gs;                              // wave-uniform
        float acc[16];
        #pragma unroll
        for (int j = 0; j < 16; ++j) acc[j] = 0.f;
        #pragma unroll 4
        for (int ci = 0; ci < 64; ++ci) {
            const float a = lds1[ci][p];
            const float* wr = Wo + ci * 64 + cg * 16;   // wave-uniform -> s_load
            #pragma unroll
            for (int j = 0; j < 16; ++j) acc[j] = fmaf(a, wr[j], acc[j]);
        }
        float* ob = out + (size_t)(b * 64 + cg * 16) * kHW + (size_t)h * kW + w0 + p;
        #pragma unroll
        for (int j = 0; j < 16; ++j) ob[(size_t)j * kHW] = acc[j];
    }
}

extern "C" void kernel_launch(void* const* d_in, const int* in_sizes, int n_in,
                              void* d_out, int out_size, void* d_ws, size_t ws_size,
                              hipStream_t stream) {
    const float* inp = (const float*)d_in[0];
    const float* Wv  = (const float*)d_in[1];
    const float* bv  = (const float*)d_in[2];
    const float* Wdw = (const float*)d_in[3];
    const float* bdw = (const float*)d_in[4];
    const float* Wom = (const float*)d_in[5];
    const float* bom = (const float*)d_in[6];
    const float* Wo  = (const float*)d_in[7];
    float* outp = (float*)d_out;
    unsigned short* value = (unsigned short*)d_ws;   // [b][g][yx][16] bf16 = 37.7 MB

    k_value<<<kNB, 256, 0, stream>>>(inp, Wv, bv, value);
    k_main<<<kNB, 256, 0, stream>>>(inp, Wdw, bdw, Wom, bom, Wo, value, outp);
}